// Round 2
// baseline (714.107 us; speedup 1.0000x reference)
//
#include <hip/hip_runtime.h>
#include <hip/hip_bf16.h>

#define DIM 128
#define EPSV 1e-8f
#define RSQRT_D 0.08838834764831845f

typedef __attribute__((ext_vector_type(8))) short bf16x8;
typedef __attribute__((ext_vector_type(4))) float f32x4;

__device__ __forceinline__ unsigned short f2b(float f) {
  union { float f; unsigned u; } v; v.f = f;
  unsigned r = v.u + 0x7FFF + ((v.u >> 16) & 1);
  return (unsigned short)(r >> 16);
}
__device__ __forceinline__ float b2f(unsigned short s) {
  union { unsigned u; float f; } v; v.u = ((unsigned)s) << 16;
  return v.f;
}
__device__ __forceinline__ float silu_f(float x) { return x / (1.f + __expf(-x)); }

// swizzled short-index into a [rows][128] bf16 tile (XOR bits 3-5 with row&7)
__device__ __forceinline__ int swz(int row, int col) {
  return (row * DIM + col) ^ ((row & 7) << 3);
}

// ---------------- K0: convert weights to bf16 ----------------
__global__ void k_prep_weights(const float* __restrict__ W1,
                               const float* __restrict__ W2,
                               const float* __restrict__ Wout,
                               unsigned short* __restrict__ wbf) {
  int i = blockIdx.x * blockDim.x + threadIdx.x;  // 0..49151
  if (i < 16384)        wbf[i] = f2b(W1[i]);
  else if (i < 32768)   wbf[i] = f2b(W2[i - 16384]);
  else if (i < 49152)   wbf[i] = f2b(Wout[i - 32768]);
}

// ---------------- K1: per-molecule prep ----------------
// kt[b][j] = sum_i k_b[i] * Wq[i][j] / sqrt(D);  kb[b] = k_b . bq / sqrt(D)
__global__ void k_mol(const float* __restrict__ Q, const float* __restrict__ Wq,
                      const float* __restrict__ bq, const float* __restrict__ Wk,
                      const float* __restrict__ Wv,
                      float* __restrict__ kt, float* __restrict__ kb,
                      float* __restrict__ vmol) {
  int b = blockIdx.x, j = threadIdx.x;
  float Qb = Q[b];
  float e0 = fmaxf(Qb, 0.f), e1 = fmaxf(-Qb, 0.f);
  float ek0 = e0 / fmaxf(e0, 1.f), ek1 = e1 / fmaxf(e1, 1.f);
  float kj = ek0 * Wk[j * 2] + ek1 * Wk[j * 2 + 1];
  vmol[b * DIM + j] = e0 * Wv[j * 2] + e1 * Wv[j * 2 + 1];
  __shared__ float ksh[DIM];
  ksh[j] = kj;
  __syncthreads();
  float acc = 0.f;
#pragma unroll 8
  for (int i = 0; i < DIM; ++i) acc += ksh[i] * Wq[i * DIM + j];
  kt[b * DIM + j] = acc * RSQRT_D;
  __syncthreads();
  ksh[j] = kj * bq[j];
  __syncthreads();
  for (int s2 = 64; s2 > 0; s2 >>= 1) {
    if (j < s2) ksh[j] += ksh[j + s2];
    __syncthreads();
  }
  if (j == 0) kb[b] = ksh[0] * RSQRT_D;
}

// ---------------- K2: per-atom a + segment sum ----------------
__global__ void k_atoms(const float* __restrict__ emb, const int* __restrict__ seg,
                        const float* __restrict__ kt, const float* __restrict__ kb,
                        float* __restrict__ a_out, float* __restrict__ anorm,
                        int N, int chunk) {
  int wid = (blockIdx.x * blockDim.x + threadIdx.x) >> 6;
  int lane = threadIdx.x & 63;
  int hh = lane >> 5;    // which atom of the pair
  int l32 = lane & 31;   // float4 slot within row
  long start = (long)wid * chunk;
  long end = start + chunk;
  if (end > N) end = N;
  int cur_b = -1;
  float racc = 0.f;
  bool leader = (l32 == 0);
  for (long n0 = start; n0 < end; n0 += 2) {
    long n = n0 + hh;
    bool valid = (n < end);
    long nn = valid ? n : (end - 1);
    int b = seg[nn];
    float4 e4 = ((const float4*)(emb + nn * DIM))[l32];
    float4 k4 = ((const float4*)(kt + (long)b * DIM))[l32];
    float p = e4.x * k4.x + e4.y * k4.y + e4.z * k4.z + e4.w * k4.w;
    p += __shfl_xor(p, 1);
    p += __shfl_xor(p, 2);
    p += __shfl_xor(p, 4);
    p += __shfl_xor(p, 8);
    p += __shfl_xor(p, 16);
    float dot = p + kb[b];
    float av = fmaxf(dot, 0.f) + log1pf(__expf(-fabsf(dot)));
    if (leader && valid) {
      a_out[n] = av;
      if (b != cur_b) {
        if (cur_b >= 0) atomicAdd(anorm + cur_b, racc);
        cur_b = b;
        racc = av;
      } else {
        racc += av;
      }
    }
  }
  if (leader && cur_b >= 0) atomicAdd(anorm + cur_b, racc);
}

// ---------------- K3: fused residual MLP (3 GEMMs, bf16 MFMA) ----------------
__device__ __forceinline__ void gemm128(f32x4 (&acc)[4][4],
                                        const unsigned short* TA,
                                        const unsigned short* WB,
                                        int wrow, int wcol, int lane) {
  f32x4 z = {0.f, 0.f, 0.f, 0.f};
#pragma unroll
  for (int rf = 0; rf < 4; ++rf)
#pragma unroll
    for (int cf = 0; cf < 4; ++cf) acc[rf][cf] = z;
#pragma unroll
  for (int kc = 0; kc < 4; ++kc) {
    int kof = kc * 32 + (lane >> 4) * 8;
    bf16x8 af[4], bfr[4];
#pragma unroll
    for (int rf = 0; rf < 4; ++rf)
      af[rf] = *(const bf16x8*)&TA[swz(wrow + rf * 16 + (lane & 15), kof)];
#pragma unroll
    for (int cf = 0; cf < 4; ++cf)
      bfr[cf] = *(const bf16x8*)&WB[swz(wcol + cf * 16 + (lane & 15), kof)];
#pragma unroll
    for (int rf = 0; rf < 4; ++rf)
#pragma unroll
      for (int cf = 0; cf < 4; ++cf)
        acc[rf][cf] = __builtin_amdgcn_mfma_f32_16x16x32_bf16(af[rf], bfr[cf],
                                                              acc[rf][cf], 0, 0, 0);
  }
}

__launch_bounds__(256, 1)
__global__ void k_fused(const int* __restrict__ seg, const float* __restrict__ a_in,
                        const float* __restrict__ anorm, const float* __restrict__ vmol,
                        const unsigned short* __restrict__ wbf,
                        const float* __restrict__ b1, const float* __restrict__ b2,
                        float* __restrict__ out, int N, int ntiles) {
  __shared__ unsigned short Wl[3][DIM * DIM];  // 96 KB
  __shared__ unsigned short T0[DIM * DIM];     // 32 KB (x)
  __shared__ unsigned short T1[DIM * DIM];     // 32 KB (activations)

  int tid = threadIdx.x;
  int lane = tid & 63, w = tid >> 6;
  int wrow = (w >> 1) * 64, wcol = (w & 1) * 64;

  // stage weights into LDS (swizzled), once per block
  for (int c = tid; c < 3 * (DIM * DIM / 8); c += 256) {
    int g = c >> 11;           // 2048 16B-chunks per weight
    int cc = c & 2047;
    int row = cc >> 4;         // 16 chunks per row
    int col = (cc & 15) * 8;
    bf16x8 v = *(const bf16x8*)(wbf + g * DIM * DIM + row * DIM + col);
    *(bf16x8*)&Wl[g][swz(row, col)] = v;
  }
  __syncthreads();

  for (int tile = blockIdx.x; tile < ntiles; tile += gridDim.x) {
    long R0 = (long)tile * DIM;

    // ---- build x (T0) and silu(x) (T1) tiles ----
    {
      int row = tid >> 1;
      int halfc = (tid & 1) * 64;
      long n = R0 + row;
      float s = 0.f;
      long b = 0;
      if (n < N) {
        b = seg[n];
        s = a_in[n] / (anorm[b] + EPSV);
      }
      const float4* vp = (const float4*)(vmol + b * DIM + halfc);
#pragma unroll
      for (int c8 = 0; c8 < 8; ++c8) {
        int col = halfc + c8 * 8;
        float4 v0 = vp[c8 * 2];
        float4 v1 = vp[c8 * 2 + 1];
        float xv[8] = {s * v0.x, s * v0.y, s * v0.z, s * v0.w,
                       s * v1.x, s * v1.y, s * v1.z, s * v1.w};
        bf16x8 xs, ss;
#pragma unroll
        for (int e = 0; e < 8; ++e) {
          xs[e] = (short)f2b(xv[e]);
          ss[e] = (short)f2b(silu_f(xv[e]));
        }
        *(bf16x8*)&T0[swz(row, col)] = xs;
        *(bf16x8*)&T1[swz(row, col)] = ss;
      }
    }
    __syncthreads();

    f32x4 acc[4][4];

    // ---- GEMM1: silu(x) @ W1^T ----
    gemm128(acc, T1, Wl[0], wrow, wcol, lane);
#pragma unroll
    for (int rf = 0; rf < 4; ++rf)
#pragma unroll
      for (int cf = 0; cf < 4; ++cf) {
        int col = wcol + cf * 16 + (lane & 15);
        float bb = b1[col];
#pragma unroll
        for (int r = 0; r < 4; ++r) acc[rf][cf][r] = silu_f(acc[rf][cf][r] + bb);
      }
    __syncthreads();
#pragma unroll
    for (int rf = 0; rf < 4; ++rf)
#pragma unroll
      for (int cf = 0; cf < 4; ++cf) {
        int col = wcol + cf * 16 + (lane & 15);
#pragma unroll
        for (int r = 0; r < 4; ++r) {
          int row = wrow + rf * 16 + (lane >> 4) * 4 + r;
          T1[swz(row, col)] = f2b(acc[rf][cf][r]);
        }
      }
    __syncthreads();

    // ---- GEMM2: u @ W2^T ; h = x + . + b2 ; silu(h) ----
    gemm128(acc, T1, Wl[1], wrow, wcol, lane);
#pragma unroll
    for (int rf = 0; rf < 4; ++rf)
#pragma unroll
      for (int cf = 0; cf < 4; ++cf) {
        int col = wcol + cf * 16 + (lane & 15);
        float bb = b2[col];
#pragma unroll
        for (int r = 0; r < 4; ++r) {
          int row = wrow + rf * 16 + (lane >> 4) * 4 + r;
          float xv = b2f(T0[swz(row, col)]);
          acc[rf][cf][r] = silu_f(xv + acc[rf][cf][r] + bb);
        }
      }
    __syncthreads();
#pragma unroll
    for (int rf = 0; rf < 4; ++rf)
#pragma unroll
      for (int cf = 0; cf < 4; ++cf) {
        int col = wcol + cf * 16 + (lane & 15);
#pragma unroll
        for (int r = 0; r < 4; ++r) {
          int row = wrow + rf * 16 + (lane >> 4) * 4 + r;
          T1[swz(row, col)] = f2b(acc[rf][cf][r]);
        }
      }
    __syncthreads();

    // ---- GEMM3: silu(h) @ Wout^T ; store ----
    gemm128(acc, T1, Wl[2], wrow, wcol, lane);
#pragma unroll
    for (int rf = 0; rf < 4; ++rf) {
#pragma unroll
      for (int r = 0; r < 4; ++r) {
        long n = R0 + wrow + rf * 16 + (lane >> 4) * 4 + r;
        if (n < N) {
          float* op = out + n * DIM + wcol + (lane & 15);
#pragma unroll
          for (int cf = 0; cf < 4; ++cf) op[cf * 16] = acc[rf][cf][r];
        }
      }
    }
    __syncthreads();  // protect T0/T1 before next tile
  }
}

extern "C" void kernel_launch(void* const* d_in, const int* in_sizes, int n_in,
                              void* d_out, int out_size, void* d_ws, size_t ws_size,
                              hipStream_t stream) {
  const float* emb  = (const float*)d_in[0];
  const float* Q    = (const float*)d_in[1];
  const int*   seg  = (const int*)d_in[2];
  const float* Wq   = (const float*)d_in[3];
  const float* bq   = (const float*)d_in[4];
  const float* Wk   = (const float*)d_in[5];
  const float* Wv   = (const float*)d_in[6];
  const float* W1   = (const float*)d_in[7];
  const float* b1   = (const float*)d_in[8];
  const float* W2   = (const float*)d_in[9];
  const float* b2   = (const float*)d_in[10];
  const float* Wout = (const float*)d_in[11];
  int N = in_sizes[2];
  int B = in_sizes[1];
  float* out = (float*)d_out;

  char* ws = (char*)d_ws;
  float* kt    = (float*)ws;                      // B*128 f32
  float* vmol  = kt + (size_t)B * DIM;            // B*128 f32
  float* a_buf = vmol + (size_t)B * DIM;          // N f32
  float* kb    = a_buf + N;                       // B f32
  float* anorm = kb + B;                          // B f32
  unsigned short* wbf = (unsigned short*)(anorm + B);  // 3*128*128 bf16

  hipMemsetAsync(anorm, 0, B * sizeof(float), stream);
  k_prep_weights<<<192, 256, 0, stream>>>(W1, W2, Wout, wbf);
  k_mol<<<B, DIM, 0, stream>>>(Q, Wq, bq, Wk, Wv, kt, kb, vmol);

  int blocks2 = 2048;
  int waves = blocks2 * 256 / 64;
  int chunk = (N + waves - 1) / waves;
  k_atoms<<<blocks2, 256, 0, stream>>>(emb, seg, kt, kb, a_buf, anorm, N, chunk);

  int ntiles = (N + DIM - 1) / DIM;
  k_fused<<<256, 256, 0, stream>>>(seg, a_buf, anorm, vmol, wbf, b1, b2, out, N, ntiles);
}